// Round 7
// baseline (342.985 us; speedup 1.0000x reference)
//
#include <hip/hip_runtime.h>
#include <cstdint>

using u16 = unsigned short;
using u32 = unsigned int;

constexpr int kB  = 4096;
constexpr int kE  = 512;
constexpr int kT  = 32;
constexpr int kH  = 256;
constexpr int kIT = 5;
constexpr float kEPS = 1e-6f;

typedef __attribute__((ext_vector_type(8)))  short short8;
typedef __attribute__((ext_vector_type(16))) float floatx16;
typedef __attribute__((ext_vector_type(8)))  u16   ushort8;
typedef __attribute__((ext_vector_type(4)))  float floatv4;  // native vec for nt builtins

__device__ __forceinline__ u16 f2bf(float f) {
  u32 u = __builtin_bit_cast(u32, f);
  return (u16)((u + 0x7fffu + ((u >> 16) & 1u)) >> 16);
}

__device__ __forceinline__ floatx16 mfma32(short8 a, short8 b, floatx16 c) {
  return __builtin_amdgcn_mfma_f32_32x32x16_bf16(a, b, c, 0, 0, 0);
}

__device__ __forceinline__ void ntstore4(float* p, float4 v) {
  __builtin_nontemporal_store(__builtin_bit_cast(floatv4, v), (floatv4*)p);
}

// async global->LDS, 16B/lane; LDS dest = wave-uniform base (+ HW lane*16),
// global src = per-lane address. Our packed chunks are exactly 64 lanes x 16B.
__device__ __forceinline__ void gload16(const u16* gsrc, u16* ldst) {
  __builtin_amdgcn_global_load_lds(
      (const __attribute__((address_space(1))) u32*)gsrc,
      (__attribute__((address_space(3))) u32*)ldst, 16, 0, 0);
}

// ---------------- pack_x (R6, verified): coalesced LDS transpose ----------------
// xp chunk c = slab*64 + ks*2 + mt ; lane l holds row=slab*64+mt*32+(l&31),
// k = ks*16+(l>>5)*8+j
__global__ __launch_bounds__(256) void pack_x_kernel(
    const float* __restrict__ x, u16* __restrict__ xp) {
  __shared__ __attribute__((aligned(16))) float tile[64 * 132];
  const int slab = blockIdx.x >> 2;
  const int kg   = blockIdx.x & 3;
  const int tid  = threadIdx.x;

  const int r0 = tid >> 5;          // 0..7
  const int c0 = (tid & 31) * 4;    // 0..124
#pragma unroll
  for (int p = 0; p < 8; ++p) {
    const int r = p * 8 + r0;
    const float4 v = *(const float4*)(x + (size_t)(slab * 64 + r) * kE + kg * 128 + c0);
    *(float4*)(tile + r * 132 + c0) = v;
  }
  __syncthreads();

  const int wv = tid >> 6, lane = tid & 63;
#pragma unroll
  for (int q = 0; q < 4; ++q) {
    const int cc   = wv * 4 + q;       // 0..15
    const int ks_l = cc >> 1;          // 0..7
    const int mt   = cc & 1;
    const int rl   = mt * 32 + (lane & 31);
    const int kl   = ks_l * 16 + (lane >> 5) * 8;
    const float4 f0 = *(const float4*)(tile + rl * 132 + kl);
    const float4 f1 = *(const float4*)(tile + rl * 132 + kl + 4);
    ushort8 o;
    o[0] = f2bf(f0.x); o[1] = f2bf(f0.y); o[2] = f2bf(f0.z); o[3] = f2bf(f0.w);
    o[4] = f2bf(f1.x); o[5] = f2bf(f1.y); o[6] = f2bf(f1.z); o[7] = f2bf(f1.w);
    const int c = slab * 64 + (kg * 8 + ks_l) * 2 + mt;
    *(ushort8*)(xp + (size_t)c * 512 + lane * 8) = o;
  }
}

// ---------------- pack_w (R6, verified): LDS transpose, cached loads ----------
// wp chunk c = t*512 + ks*16 + ntile*2 + mat : lane l holds n=ntile*32+(l&31),
// k=ks*16+(l>>5)*8+j
__global__ __launch_bounds__(256) void pack_w_kernel(
    const float* __restrict__ w_in, const float* __restrict__ w_val,
    u16* __restrict__ wp) {
  __shared__ __attribute__((aligned(16))) float tile[64 * 68];
  const int wb   = blockIdx.x;
  const int tl   = wb & 31;
  const int et   = tl >> 2;
  const int ht   = tl & 3;
  const int tm   = wb >> 5;
  const int t    = tm >> 1, mat = tm & 1;
  const int tid  = threadIdx.x;
  const float* src = (mat ? w_val : w_in) + (size_t)t * kE * kH +
                     (size_t)(et * 64) * kH + ht * 64;
  const int lrow = tid >> 4, lc4 = (tid & 15) * 4;
#pragma unroll
  for (int p = 0; p < 4; ++p) {
    const int e = lrow + p * 16;
    const float4 v = *(const float4*)(src + (size_t)e * kH + lc4);
    tile[e * 68 + lc4 + 0] = v.x; tile[e * 68 + lc4 + 1] = v.y;
    tile[e * 68 + lc4 + 2] = v.z; tile[e * 68 + lc4 + 3] = v.w;
  }
  __syncthreads();
  const int ks_l = tid >> 6, lane = tid & 63;
  const int kloc = ks_l * 16 + (lane >> 5) * 8;
#pragma unroll
  for (int nt_l = 0; nt_l < 2; ++nt_l) {
    const int nloc = nt_l * 32 + (lane & 31);
    ushort8 o;
#pragma unroll
    for (int j = 0; j < 8; ++j) o[j] = f2bf(tile[(kloc + j) * 68 + nloc]);
    const int c = t * 512 + (et * 4 + ks_l) * 16 + (ht * 2 + nt_l) * 2 + mat;
    *(ushort8*)(wp + (size_t)c * 512 + lane * 8) = o;
  }
}

// ---------------- fused R11: T3+T4 2-barrier counted-vmcnt shared staging ------
// 512 threads = 8 waves as 2M x 4N: wave (wm=wv>>2, wn=wv&3) owns rows wm*32..+32,
// cols wn*64..+64 (dual GEMM) -> acc = 2x2 floatx16 = 64 regs, 4 waves/SIMD kept.
// Per phase (K=16): all waves cooperatively gload_lds the FULL B slice (16 chunks,
// 2/wave, uniform vmcnt counts) into a 2x16KB double buffer; A (1 chunk/wave, 4x
// less redundancy than R10) in a 2-slot reg ring. Body:
//   stage(p+1) -> s_waitcnt vmcnt(3) [counted: allows p+1's 3 ops in flight,
//   guarantees p's staged] -> s_barrier -> ds_read 4 B frags + 4 MFMA ->
//   sched_barrier -> s_barrier [reads complete before buf's next writer].
// Raw s_barrier (no vmcnt(0) drain - the R7 killer). Block L2 traffic/phase:
// 18KB vs R10's 32KB. Epilogue identical except acc dump (guard wm==mt, new col).
__global__ __launch_bounds__(512, 4) void fused_kernel(
    const u16* __restrict__ xp, const u16* __restrict__ wp,
    const float* __restrict__ alphas, const float* __restrict__ scales,
    const float* __restrict__ gamma, const float* __restrict__ beta,
    float* __restrict__ out) {
  __shared__ __attribute__((aligned(16))) u16 sB[2][16 * 512];  // 2 x 16KB
  float* sAcc = (float*)sB;  // 32KB epilogue scratch, aliases both buffers

  const int tid  = threadIdx.x;
  const int wv   = tid >> 6;         // 0..7
  const int lane = tid & 63;
  const int l31  = lane & 31;
  const int h    = lane >> 5;
  const int wm   = wv >> 2;          // 0..1 : row half (mt)
  const int wn   = wv & 3;           // 0..3 : 64-col group

  const int bid  = blockIdx.x;
  const int xcd  = bid & 7;
  const int r_   = bid >> 3;
  const int st   = r_ >> 6;
  const int wi   = r_ & 63;
  const int t    = xcd * 4 + (wi >> 4);
  const int slab = st * 16 + (wi & 15);

  // chunk = 512 u16 = 1KB = 64 lanes x 16B
  const u16* xsrc = xp + (size_t)slab * (32 * 2 * 512) + lane * 8;  // A: chunk p*2+wm
  const u16* wsrc = wp + (size_t)t * (32 * 16 * 512) + lane * 8;    // B: chunk p*16+cb

  floatx16 ai[2], av[2];   // [nt]: rows wm*32.., cols wn*64 + nt*32
#pragma unroll
  for (int n = 0; n < 2; ++n) { ai[n] = (floatx16)0.f; av[n] = (floatx16)0.f; }

  short8 A[2];  // 2-slot reg ring for this wave's A chunk

  // stage batch p into buf: this wave's 2 B chunks {wv*2, wv*2+1}
  auto stageB = [&](int p, int buf) {
    const int cb = wv * 2;
    gload16(wsrc + (size_t)(p * 16 + cb) * 512,     &sB[buf][cb * 512]);
    gload16(wsrc + (size_t)(p * 16 + cb + 1) * 512, &sB[buf][(cb + 1) * 512]);
  };

  // prologue: batch 0 staged, A[0] loaded
  stageB(0, 0);
  A[0] = *(const short8*)(xsrc + 0 * 1024 + wm * 512);

#pragma unroll
  for (int p = 0; p < 32; ++p) {
    if (p < 31) {
      stageB(p + 1, (p + 1) & 1);
      A[(p + 1) & 1] = *(const short8*)(xsrc + (size_t)(p + 1) * 1024 + wm * 512);
    }
    // counted wall: allow phase p+1's 3 ops in flight; batch p guaranteed landed
    if (p < 31) { asm volatile("s_waitcnt vmcnt(3)" ::: "memory"); }
    else        { asm volatile("s_waitcnt vmcnt(0)" ::: "memory"); }
    __builtin_amdgcn_sched_barrier(0);
    __builtin_amdgcn_s_barrier();   // all waves' batch-p stage complete
    __builtin_amdgcn_sched_barrier(0);

    const u16* sBp = &sB[p & 1][0] + lane * 8;
    const short8 BI0 = *(const short8*)(sBp + ((wn * 2 + 0) * 2 + 0) * 512);
    const short8 BV0 = *(const short8*)(sBp + ((wn * 2 + 0) * 2 + 1) * 512);
    const short8 BI1 = *(const short8*)(sBp + ((wn * 2 + 1) * 2 + 0) * 512);
    const short8 BV1 = *(const short8*)(sBp + ((wn * 2 + 1) * 2 + 1) * 512);
    const short8 Ac = A[p & 1];
    ai[0] = mfma32(Ac, BI0, ai[0]);
    av[0] = mfma32(Ac, BV0, av[0]);
    ai[1] = mfma32(Ac, BI1, ai[1]);
    av[1] = mfma32(Ac, BV1, av[1]);
    __builtin_amdgcn_sched_barrier(0);
    __builtin_amdgcn_s_barrier();   // reads of buf[p&1] done -> p+2's stage may write it
  }

  // ---- epilogue: verified R10 512-thread version; only the acc dump differs ----
  const float inv_h = 1.0f / kH;
  float al[kIT];
#pragma unroll
  for (int i = 0; i < kIT; ++i) al[i] = alphas[t * kIT + i] * inv_h;

  const int row_r = tid >> 4;        // 0..31
  const int seg   = tid & 15;        // 0..15
  const int r4    = (row_r & 7) << 2;

#pragma unroll
  for (int mt = 0; mt < 2; ++mt) {
    __syncthreads();
    if (wm == mt) {
#pragma unroll
      for (int nt = 0; nt < 2; ++nt)
#pragma unroll
        for (int q = 0; q < 16; ++q) {
          const int r   = (q & 3) + 8 * (q >> 2) + 4 * h;
          const int col = wn * 64 + nt * 32 + l31;
          sAcc[r * 256 + (col ^ ((r & 7) << 2))] = ai[nt][q];
        }
    }
    __syncthreads();

    float4 xt[4];
#pragma unroll
    for (int j = 0; j < 4; ++j) {
      xt[j] = *(const float4*)(sAcc + row_r * 256 + ((seg * 16 + 4 * j) ^ r4));
#pragma unroll
      for (int i = 0; i < 4; ++i) xt[j][i] = fmaxf(xt[j][i], 0.f);
    }

#pragma unroll
    for (int it = 0; it < kIT; ++it) {
      float4 s4 = xt[0];
#pragma unroll
      for (int j = 1; j < 4; ++j) s4 += xt[j];
      float v = s4.x + s4.y + s4.z + s4.w;
      v += __shfl_xor(v, 1, 16);
      v += __shfl_xor(v, 2, 16);
      v += __shfl_xor(v, 4, 16);
      v += __shfl_xor(v, 8, 16);
      const float m = al[it] * v;
#pragma unroll
      for (int j = 0; j < 4; ++j)
#pragma unroll
        for (int i = 0; i < 4; ++i) xt[j][i] = fmaxf(xt[j][i] - m, 0.f);
    }

    __syncthreads();
    if (wm == mt) {
#pragma unroll
      for (int nt = 0; nt < 2; ++nt)
#pragma unroll
        for (int q = 0; q < 16; ++q) {
          const int r   = (q & 3) + 8 * (q >> 2) + 4 * h;
          const int col = wn * 64 + nt * 32 + l31;
          sAcc[r * 256 + (col ^ ((r & 7) << 2))] = av[nt][q];
        }
    }
    __syncthreads();

    float4 res[4];
    float sum = 0.f, ssq = 0.f;
#pragma unroll
    for (int j = 0; j < 4; ++j) {
      const int lc = seg * 16 + 4 * j;           // logical column
      const int cb = lc ^ r4;                    // physical LDS offset
      const float4 a4 = *(const float4*)(sAcc + row_r * 256 + cb);
      const float4 sc = *(const float4*)(scales + t * kH + lc);
      float4 s;
#pragma unroll
      for (int i = 0; i < 4; ++i) {
        s[i] = sc[i] * xt[j][i] * a4[i];
        sum += s[i];
        ssq += s[i] * s[i];
      }
      res[j] = s;
    }
    sum += __shfl_xor(sum, 1, 16);  ssq += __shfl_xor(ssq, 1, 16);
    sum += __shfl_xor(sum, 2, 16);  ssq += __shfl_xor(ssq, 2, 16);
    sum += __shfl_xor(sum, 4, 16);  ssq += __shfl_xor(ssq, 4, 16);
    sum += __shfl_xor(sum, 8, 16);  ssq += __shfl_xor(ssq, 8, 16);
    const float mu  = sum * inv_h;
    const float var = ssq * inv_h - mu * mu;
    const float rs  = rsqrtf(var + kEPS);

#pragma unroll
    for (int j = 0; j < 4; ++j) {
      const int lc = seg * 16 + 4 * j;
      const int cb = lc ^ r4;
      const float4 g4 = *(const float4*)(gamma + t * kH + lc);
      const float4 b4 = *(const float4*)(beta + t * kH + lc);
      float4 o;
#pragma unroll
      for (int i = 0; i < 4; ++i) o[i] = (res[j][i] - mu) * rs * g4[i] + b4[i];
      *(float4*)(sAcc + row_r * 256 + cb) = o;
    }
    __syncthreads();

    // coalesced non-temporal sweep: 8 waves x 4 rows
#pragma unroll
    for (int r8 = 0; r8 < 4; ++r8) {
      const int rr = wv * 4 + r8;
      const int rb = (rr & 7) << 2;
      const float4 v = *(const float4*)(sAcc + rr * 256 + ((4 * lane) ^ rb));
      ntstore4(out + (size_t)(slab * 64 + mt * 32 + rr) * (kT * kH) + t * kH + 4 * lane, v);
    }
  }
}

extern "C" void kernel_launch(void* const* d_in, const int* in_sizes, int n_in,
                              void* d_out, int out_size, void* d_ws, size_t ws_size,
                              hipStream_t stream) {
  const float* x      = (const float*)d_in[0];
  const float* w_in   = (const float*)d_in[1];
  const float* w_val  = (const float*)d_in[2];
  const float* alphas = (const float*)d_in[3];
  const float* scales = (const float*)d_in[4];
  const float* gamma  = (const float*)d_in[5];
  const float* beta   = (const float*)d_in[6];
  float* out = (float*)d_out;

  // ws: xp 4MB (64*32*2 chunks * 1KB) | wp 16MB (32*32*16 chunks * 1KB)
  u16* xp = (u16*)d_ws;
  u16* wp = xp + (size_t)64 * 32 * 2 * 512;

  pack_x_kernel<<<256, 256, 0, stream>>>(x, xp);
  pack_w_kernel<<<2048, 256, 0, stream>>>(w_in, w_val, wp);
  fused_kernel<<<kT * (kB / 64), 512, 0, stream>>>(xp, wp, alphas, scales,
                                                   gamma, beta, out);
}

// Round 8
// 329.521 us; speedup vs baseline: 1.0409x; 1.0409x over previous
//
#include <hip/hip_runtime.h>
#include <cstdint>

using u16 = unsigned short;
using u32 = unsigned int;

constexpr int kB  = 4096;
constexpr int kE  = 512;
constexpr int kT  = 32;
constexpr int kH  = 256;
constexpr int kIT = 5;
constexpr float kEPS = 1e-6f;

typedef __attribute__((ext_vector_type(8)))  short short8;
typedef __attribute__((ext_vector_type(16))) float floatx16;
typedef __attribute__((ext_vector_type(8)))  u16   ushort8;
typedef __attribute__((ext_vector_type(4)))  float floatv4;  // native vec for nt builtins

__device__ __forceinline__ u16 f2bf(float f) {
  u32 u = __builtin_bit_cast(u32, f);
  return (u16)((u + 0x7fffu + ((u >> 16) & 1u)) >> 16);
}

__device__ __forceinline__ floatx16 mfma32(short8 a, short8 b, floatx16 c) {
  return __builtin_amdgcn_mfma_f32_32x32x16_bf16(a, b, c, 0, 0, 0);
}

__device__ __forceinline__ void ntstore4(float* p, float4 v) {
  __builtin_nontemporal_store(__builtin_bit_cast(floatv4, v), (floatv4*)p);
}

// async global->LDS, 16B/lane; LDS dest = wave-uniform base (+ HW lane*16),
// global src = per-lane address. Our packed chunks are exactly 64 lanes x 16B.
__device__ __forceinline__ void gload16(const u16* gsrc, u16* ldst) {
  __builtin_amdgcn_global_load_lds(
      (const __attribute__((address_space(1))) u32*)gsrc,
      (__attribute__((address_space(3))) u32*)ldst, 16, 0, 0);
}

// ---------------- pack_x (R6, verified): coalesced LDS transpose ----------------
// xp chunk c = slab*64 + ks*2 + mt ; lane l holds row=slab*64+mt*32+(l&31),
// k = ks*16+(l>>5)*8+j
__global__ __launch_bounds__(256) void pack_x_kernel(
    const float* __restrict__ x, u16* __restrict__ xp) {
  __shared__ __attribute__((aligned(16))) float tile[64 * 132];
  const int slab = blockIdx.x >> 2;
  const int kg   = blockIdx.x & 3;
  const int tid  = threadIdx.x;

  const int r0 = tid >> 5;          // 0..7
  const int c0 = (tid & 31) * 4;    // 0..124
#pragma unroll
  for (int p = 0; p < 8; ++p) {
    const int r = p * 8 + r0;
    const float4 v = *(const float4*)(x + (size_t)(slab * 64 + r) * kE + kg * 128 + c0);
    *(float4*)(tile + r * 132 + c0) = v;
  }
  __syncthreads();

  const int wv = tid >> 6, lane = tid & 63;
#pragma unroll
  for (int q = 0; q < 4; ++q) {
    const int cc   = wv * 4 + q;       // 0..15
    const int ks_l = cc >> 1;          // 0..7
    const int mt   = cc & 1;
    const int rl   = mt * 32 + (lane & 31);
    const int kl   = ks_l * 16 + (lane >> 5) * 8;
    const float4 f0 = *(const float4*)(tile + rl * 132 + kl);
    const float4 f1 = *(const float4*)(tile + rl * 132 + kl + 4);
    ushort8 o;
    o[0] = f2bf(f0.x); o[1] = f2bf(f0.y); o[2] = f2bf(f0.z); o[3] = f2bf(f0.w);
    o[4] = f2bf(f1.x); o[5] = f2bf(f1.y); o[6] = f2bf(f1.z); o[7] = f2bf(f1.w);
    const int c = slab * 64 + (kg * 8 + ks_l) * 2 + mt;
    *(ushort8*)(xp + (size_t)c * 512 + lane * 8) = o;
  }
}

// ---------------- pack_w (R6, verified): LDS transpose, cached loads ----------
// wp chunk c = t*512 + ks*16 + ntile*2 + mat : lane l holds n=ntile*32+(l&31),
// k=ks*16+(l>>5)*8+j
__global__ __launch_bounds__(256) void pack_w_kernel(
    const float* __restrict__ w_in, const float* __restrict__ w_val,
    u16* __restrict__ wp) {
  __shared__ __attribute__((aligned(16))) float tile[64 * 68];
  const int wb   = blockIdx.x;
  const int tl   = wb & 31;
  const int et   = tl >> 2;
  const int ht   = tl & 3;
  const int tm   = wb >> 5;
  const int t    = tm >> 1, mat = tm & 1;
  const int tid  = threadIdx.x;
  const float* src = (mat ? w_val : w_in) + (size_t)t * kE * kH +
                     (size_t)(et * 64) * kH + ht * 64;
  const int lrow = tid >> 4, lc4 = (tid & 15) * 4;
#pragma unroll
  for (int p = 0; p < 4; ++p) {
    const int e = lrow + p * 16;
    const float4 v = *(const float4*)(src + (size_t)e * kH + lc4);
    tile[e * 68 + lc4 + 0] = v.x; tile[e * 68 + lc4 + 1] = v.y;
    tile[e * 68 + lc4 + 2] = v.z; tile[e * 68 + lc4 + 3] = v.w;
  }
  __syncthreads();
  const int ks_l = tid >> 6, lane = tid & 63;
  const int kloc = ks_l * 16 + (lane >> 5) * 8;
#pragma unroll
  for (int nt_l = 0; nt_l < 2; ++nt_l) {
    const int nloc = nt_l * 32 + (lane & 31);
    ushort8 o;
#pragma unroll
    for (int j = 0; j < 8; ++j) o[j] = f2bf(tile[(kloc + j) * 68 + nloc]);
    const int c = t * 512 + (et * 4 + ks_l) * 16 + (ht * 2 + nt_l) * 2 + mat;
    *(ushort8*)(wp + (size_t)c * 512 + lane * 8) = o;
  }
}

// ---------------- fused R12: 128x256 block, cooperative K32 staging -------------
// 1024 threads = 16 waves (4M x 4N); wave (wm4, wn) owns rows wm4*32, cols wn*64
// dual -> acc 64 regs, 4 waves/SIMD. Per K=32 superphase: block stages A 8 chunks
// + B 32 chunks = 40KB ONCE via gload_lds (dbuf 80KB); 128 MFMAs consume it ->
// 3.2 MFMA/KB (R10: 1.0) -> per-CU L2 demand ~40 B/cyc < ~56 supply. Counted
// per-wave vmcnt (waves 0-7 stage 3 chunks incl. one A; waves 8-15 stage 2), raw
// s_barriers (no drains), 2 barriers per ~1024 CU-cyc of work (4x coarser than
// R11's failed schedule). 1 block/CU; supertile keeps each XCD's 4-token W set
// L2-resident across all 4 slab rounds (t independent of st).
__global__ __launch_bounds__(1024, 4) void fused_kernel(
    const u16* __restrict__ xp, const u16* __restrict__ wp,
    const float* __restrict__ alphas, const float* __restrict__ scales,
    const float* __restrict__ gamma, const float* __restrict__ beta,
    float* __restrict__ out) {
  __shared__ __attribute__((aligned(16))) u16 sStage[2][40 * 512];  // 80 KB
  float* sAcc = (float*)sStage;  // 32KB epilogue scratch, aliases buffer 0

  const int tid  = threadIdx.x;
  const int wv   = tid >> 6;         // 0..15
  const int lane = tid & 63;
  const int l31  = lane & 31;
  const int h    = lane >> 5;
  const int wm4  = wv >> 2;          // 0..3 : 32-row tile
  const int wn   = wv & 3;           // 0..3 : 64-col group

  const int bid  = blockIdx.x;
  const int xcd  = bid & 7;
  const int r_   = bid >> 3;         // 0..127
  const int st   = r_ >> 5;          // 0..3 slab round
  const int wi   = r_ & 31;
  const int t    = xcd * 4 + (wi >> 3);
  const int sl2  = st * 8 + (wi & 7);   // 128-row slab 0..31

  // ---- staging roles: 40 chunks (A slots 0..7 = ksl*4+mt4, B slots 8..39 =
  // 8 + ksl*16 + ntile*2 + mat). waves 0-7 stage 3 chunks, waves 8-15 stage 2.
  const int nrole = (wv < 8) ? 3 : 2;
  const int s0    = (wv < 8) ? (wv * 3) : (24 + (wv - 8) * 2);
  const u16* rsrc[3]; int rstride[3]; int rslot[3];
#pragma unroll
  for (int r = 0; r < 3; ++r) {
    int s = s0 + r; if (s > 39) s = 39;   // clamp unused role
    rslot[r] = s;
    if (s < 8) {  // A chunk: xp chunk (sl2*2 + (mt4>>1))*64 + ks*2 + (mt4&1)
      const int ksl = s >> 2, m4 = s & 3;
      rsrc[r] = xp + (size_t)((sl2 * 2 + (m4 >> 1)) * 64 + ksl * 2 + (m4 & 1)) * 512
                   + lane * 8;
      rstride[r] = 4 * 512;               // +4 chunks per superphase (K32)
    } else {      // B chunk b = s-8 : wp chunk t*512 + P*32 + b
      const int b = s - 8;
      rsrc[r] = wp + (size_t)t * (512 * 512) + (size_t)b * 512 + lane * 8;
      rstride[r] = 32 * 512;
    }
  }

  floatx16 ai[2], av[2];   // [nt]: rows wm4*32.., cols wn*64 + nt*32
#pragma unroll
  for (int n = 0; n < 2; ++n) { ai[n] = (floatx16)0.f; av[n] = (floatx16)0.f; }

  auto stage = [&](int P, int buf) {
    u16* dbase = &sStage[buf][0];
#pragma unroll
    for (int r = 0; r < 3; ++r)
      if (r < nrole)
        gload16(rsrc[r] + (size_t)P * rstride[r], dbase + rslot[r] * 512);
  };

  stage(0, 0);

#pragma unroll
  for (int P = 0; P < 16; ++P) {
    if (P < 15) stage(P + 1, (P + 1) & 1);
    // counted wall: batch P landed; batch P+1 (nrole ops) may stay in flight
    if (P < 15) {
      if (wv < 8) { asm volatile("s_waitcnt vmcnt(3)" ::: "memory"); }
      else        { asm volatile("s_waitcnt vmcnt(2)" ::: "memory"); }
    } else        { asm volatile("s_waitcnt vmcnt(0)" ::: "memory"); }
    __builtin_amdgcn_sched_barrier(0);
    __builtin_amdgcn_s_barrier();      // all waves' batch-P stage complete
    __builtin_amdgcn_sched_barrier(0);

    const u16* bb = &sStage[P & 1][0] + lane * 8;
#pragma unroll
    for (int ksl = 0; ksl < 2; ++ksl) {
      const short8 Ac = *(const short8*)(bb + (ksl * 4 + wm4) * 512);
#pragma unroll
      for (int nt = 0; nt < 2; ++nt) {
        const short8 BIc = *(const short8*)(bb + (8 + ksl * 16 + (wn * 2 + nt) * 2 + 0) * 512);
        const short8 BVc = *(const short8*)(bb + (8 + ksl * 16 + (wn * 2 + nt) * 2 + 1) * 512);
        ai[nt] = mfma32(Ac, BIc, ai[nt]);
        av[nt] = mfma32(Ac, BVc, av[nt]);
      }
    }
    __builtin_amdgcn_sched_barrier(0);
    __builtin_amdgcn_s_barrier();      // reads of buf[P&1] done before next writer
  }

  // ---- epilogue: verified family, 1024-thread mapping (32 threads/row) ----
  const float inv_h = 1.0f / kH;
  float al[kIT];
#pragma unroll
  for (int i = 0; i < kIT; ++i) al[i] = alphas[t * kIT + i] * inv_h;

  const int row_r = tid >> 5;        // 0..31
  const int seg   = tid & 31;        // 0..31 (8 H each)
  const int r4    = (row_r & 7) << 2;

#pragma unroll
  for (int mt4 = 0; mt4 < 4; ++mt4) {
    __syncthreads();
    if (wm4 == mt4) {
#pragma unroll
      for (int nt = 0; nt < 2; ++nt)
#pragma unroll
        for (int q = 0; q < 16; ++q) {
          const int r   = (q & 3) + 8 * (q >> 2) + 4 * h;
          const int col = wn * 64 + nt * 32 + l31;
          sAcc[r * 256 + (col ^ ((r & 7) << 2))] = ai[nt][q];
        }
    }
    __syncthreads();

    float4 xt[2];
#pragma unroll
    for (int j = 0; j < 2; ++j) {
      xt[j] = *(const float4*)(sAcc + row_r * 256 + ((seg * 8 + 4 * j) ^ r4));
#pragma unroll
      for (int i = 0; i < 4; ++i) xt[j][i] = fmaxf(xt[j][i], 0.f);
    }

#pragma unroll
    for (int it = 0; it < kIT; ++it) {
      float4 s4 = xt[0] + xt[1];
      float v = s4.x + s4.y + s4.z + s4.w;
      v += __shfl_xor(v, 1, 32);
      v += __shfl_xor(v, 2, 32);
      v += __shfl_xor(v, 4, 32);
      v += __shfl_xor(v, 8, 32);
      v += __shfl_xor(v, 16, 32);
      const float m = al[it] * v;
#pragma unroll
      for (int j = 0; j < 2; ++j)
#pragma unroll
        for (int i = 0; i < 4; ++i) xt[j][i] = fmaxf(xt[j][i] - m, 0.f);
    }

    __syncthreads();
    if (wm4 == mt4) {
#pragma unroll
      for (int nt = 0; nt < 2; ++nt)
#pragma unroll
        for (int q = 0; q < 16; ++q) {
          const int r   = (q & 3) + 8 * (q >> 2) + 4 * h;
          const int col = wn * 64 + nt * 32 + l31;
          sAcc[r * 256 + (col ^ ((r & 7) << 2))] = av[nt][q];
        }
    }
    __syncthreads();

    float4 res[2];
    float sum = 0.f, ssq = 0.f;
#pragma unroll
    for (int j = 0; j < 2; ++j) {
      const int lc = seg * 8 + 4 * j;            // logical column
      const int cb = lc ^ r4;                    // physical LDS offset
      const float4 a4 = *(const float4*)(sAcc + row_r * 256 + cb);
      const float4 sc = *(const float4*)(scales + t * kH + lc);
      float4 s;
#pragma unroll
      for (int i = 0; i < 4; ++i) {
        s[i] = sc[i] * xt[j][i] * a4[i];
        sum += s[i];
        ssq += s[i] * s[i];
      }
      res[j] = s;
    }
    sum += __shfl_xor(sum, 1, 32);   ssq += __shfl_xor(ssq, 1, 32);
    sum += __shfl_xor(sum, 2, 32);   ssq += __shfl_xor(ssq, 2, 32);
    sum += __shfl_xor(sum, 4, 32);   ssq += __shfl_xor(ssq, 4, 32);
    sum += __shfl_xor(sum, 8, 32);   ssq += __shfl_xor(ssq, 8, 32);
    sum += __shfl_xor(sum, 16, 32);  ssq += __shfl_xor(ssq, 16, 32);
    const float mu  = sum * inv_h;
    const float var = ssq * inv_h - mu * mu;
    const float rs  = rsqrtf(var + kEPS);

#pragma unroll
    for (int j = 0; j < 2; ++j) {
      const int lc = seg * 8 + 4 * j;
      const int cb = lc ^ r4;
      const float4 g4 = *(const float4*)(gamma + t * kH + lc);
      const float4 b4 = *(const float4*)(beta + t * kH + lc);
      float4 o;
#pragma unroll
      for (int i = 0; i < 4; ++i) o[i] = (res[j][i] - mu) * rs * g4[i] + b4[i];
      *(float4*)(sAcc + row_r * 256 + cb) = o;
    }
    __syncthreads();

    // coalesced non-temporal sweep: 32 rows x 64 float4; 1024 threads x 2
#pragma unroll
    for (int k = 0; k < 2; ++k) {
      const int rr = (tid >> 6) + k * 16;
      const int rb = (rr & 7) << 2;
      const float4 v = *(const float4*)(sAcc + rr * 256 + ((4 * lane) ^ rb));
      ntstore4(out + (size_t)(sl2 * 128 + mt4 * 32 + rr) * (kT * kH) + t * kH + 4 * lane, v);
    }
  }
}

extern "C" void kernel_launch(void* const* d_in, const int* in_sizes, int n_in,
                              void* d_out, int out_size, void* d_ws, size_t ws_size,
                              hipStream_t stream) {
  const float* x      = (const float*)d_in[0];
  const float* w_in   = (const float*)d_in[1];
  const float* w_val  = (const float*)d_in[2];
  const float* alphas = (const float*)d_in[3];
  const float* scales = (const float*)d_in[4];
  const float* gamma  = (const float*)d_in[5];
  const float* beta   = (const float*)d_in[6];
  float* out = (float*)d_out;

  // ws: xp 4MB (64*32*2 chunks * 1KB) | wp 16MB (32*32*16 chunks * 1KB)
  u16* xp = (u16*)d_ws;
  u16* wp = xp + (size_t)64 * 32 * 2 * 512;

  pack_x_kernel<<<256, 256, 0, stream>>>(x, xp);
  pack_w_kernel<<<2048, 256, 0, stream>>>(w_in, w_val, wp);
  fused_kernel<<<kT * (kB / 128), 1024, 0, stream>>>(xp, wp, alphas, scales,
                                                     gamma, beta, out);
}

// Round 9
// 313.344 us; speedup vs baseline: 1.0946x; 1.0516x over previous
//
#include <hip/hip_runtime.h>
#include <cstdint>

using u16 = unsigned short;
using u32 = unsigned int;

constexpr int kB  = 4096;
constexpr int kE  = 512;
constexpr int kT  = 32;
constexpr int kH  = 256;
constexpr int kIT = 5;
constexpr float kEPS = 1e-6f;

typedef __attribute__((ext_vector_type(8)))  short short8;
typedef __attribute__((ext_vector_type(16))) float floatx16;
typedef __attribute__((ext_vector_type(8)))  u16   ushort8;
typedef __attribute__((ext_vector_type(4)))  float floatv4;  // native vec for nt builtins

__device__ __forceinline__ u16 f2bf(float f) {
  u32 u = __builtin_bit_cast(u32, f);
  return (u16)((u + 0x7fffu + ((u >> 16) & 1u)) >> 16);
}

__device__ __forceinline__ floatx16 mfma32(short8 a, short8 b, floatx16 c) {
  return __builtin_amdgcn_mfma_f32_32x32x16_bf16(a, b, c, 0, 0, 0);
}

__device__ __forceinline__ void ntstore4(float* p, float4 v) {
  __builtin_nontemporal_store(__builtin_bit_cast(floatv4, v), (floatv4*)p);
}

// ---------------- pack_x (R6, verified): coalesced LDS transpose ----------------
// xp chunk c = slab*64 + ks*2 + mt ; lane l holds row=slab*64+mt*32+(l&31),
// k = ks*16+(l>>5)*8+j
__global__ __launch_bounds__(256) void pack_x_kernel(
    const float* __restrict__ x, u16* __restrict__ xp) {
  __shared__ __attribute__((aligned(16))) float tile[64 * 132];
  const int slab = blockIdx.x >> 2;
  const int kg   = blockIdx.x & 3;
  const int tid  = threadIdx.x;

  const int r0 = tid >> 5;          // 0..7
  const int c0 = (tid & 31) * 4;    // 0..124
#pragma unroll
  for (int p = 0; p < 8; ++p) {
    const int r = p * 8 + r0;
    const float4 v = *(const float4*)(x + (size_t)(slab * 64 + r) * kE + kg * 128 + c0);
    *(float4*)(tile + r * 132 + c0) = v;
  }
  __syncthreads();

  const int wv = tid >> 6, lane = tid & 63;
#pragma unroll
  for (int q = 0; q < 4; ++q) {
    const int cc   = wv * 4 + q;       // 0..15
    const int ks_l = cc >> 1;          // 0..7
    const int mt   = cc & 1;
    const int rl   = mt * 32 + (lane & 31);
    const int kl   = ks_l * 16 + (lane >> 5) * 8;
    const float4 f0 = *(const float4*)(tile + rl * 132 + kl);
    const float4 f1 = *(const float4*)(tile + rl * 132 + kl + 4);
    ushort8 o;
    o[0] = f2bf(f0.x); o[1] = f2bf(f0.y); o[2] = f2bf(f0.z); o[3] = f2bf(f0.w);
    o[4] = f2bf(f1.x); o[5] = f2bf(f1.y); o[6] = f2bf(f1.z); o[7] = f2bf(f1.w);
    const int c = slab * 64 + (kg * 8 + ks_l) * 2 + mt;
    *(ushort8*)(xp + (size_t)c * 512 + lane * 8) = o;
  }
}

// ---------------- pack_w (R6, verified): LDS transpose, cached loads ----------
// wp chunk c = t*512 + ks*16 + ntile*2 + mat : lane l holds n=ntile*32+(l&31),
// k=ks*16+(l>>5)*8+j
__global__ __launch_bounds__(256) void pack_w_kernel(
    const float* __restrict__ w_in, const float* __restrict__ w_val,
    u16* __restrict__ wp) {
  __shared__ __attribute__((aligned(16))) float tile[64 * 68];
  const int wb   = blockIdx.x;
  const int tl   = wb & 31;
  const int et   = tl >> 2;
  const int ht   = tl & 3;
  const int tm   = wb >> 5;
  const int t    = tm >> 1, mat = tm & 1;
  const int tid  = threadIdx.x;
  const float* src = (mat ? w_val : w_in) + (size_t)t * kE * kH +
                     (size_t)(et * 64) * kH + ht * 64;
  const int lrow = tid >> 4, lc4 = (tid & 15) * 4;
#pragma unroll
  for (int p = 0; p < 4; ++p) {
    const int e = lrow + p * 16;
    const float4 v = *(const float4*)(src + (size_t)e * kH + lc4);
    tile[e * 68 + lc4 + 0] = v.x; tile[e * 68 + lc4 + 1] = v.y;
    tile[e * 68 + lc4 + 2] = v.z; tile[e * 68 + lc4 + 3] = v.w;
  }
  __syncthreads();
  const int ks_l = tid >> 6, lane = tid & 63;
  const int kloc = ks_l * 16 + (lane >> 5) * 8;
#pragma unroll
  for (int nt_l = 0; nt_l < 2; ++nt_l) {
    const int nloc = nt_l * 32 + (lane & 31);
    ushort8 o;
#pragma unroll
    for (int j = 0; j < 8; ++j) o[j] = f2bf(tile[(kloc + j) * 68 + nloc]);
    const int c = t * 512 + (et * 4 + ks_l) * 16 + (ht * 2 + nt_l) * 2 + mat;
    *(ushort8*)(wp + (size_t)c * 512 + lane * 8) = o;
  }
}

// ---------------- fused R13: R10 K-loop (frozen) + restructured epilogue --------
// K-loop identical to R10 (best measured: 147us): 512 thr, 8 waves n-split, wave
// tile 64x32 dual, direct global->VGPR 2-slot ring, barrier-free, 4 waves/SIMD.
// Epilogue rewrite (the never-measured half): dual LDS buffers sI/sV (64KB, still
// 2 blocks/CU) -> dump ai AND av in ONE phase; read xt+a4 in one phase; 3 syncs
// per mt instead of 6; scales/gamma/beta loads overlap the IT loop.
__global__ __launch_bounds__(512, 4) void fused_kernel(
    const u16* __restrict__ xp, const u16* __restrict__ wp,
    const float* __restrict__ alphas, const float* __restrict__ scales,
    const float* __restrict__ gamma, const float* __restrict__ beta,
    float* __restrict__ out) {
  __shared__ __attribute__((aligned(16))) float sI[32 * 256];  // 32KB
  __shared__ __attribute__((aligned(16))) float sV[32 * 256];  // 32KB

  const int tid  = threadIdx.x;
  const int wv   = tid >> 6;         // 0..7
  const int lane = tid & 63;
  const int l31  = lane & 31;
  const int h    = lane >> 5;

  const int bid  = blockIdx.x;
  const int xcd  = bid & 7;
  const int r_   = bid >> 3;
  const int st   = r_ >> 6;
  const int wi   = r_ & 63;
  const int t    = xcd * 4 + (wi >> 4);
  const int slab = st * 16 + (wi & 15);

  // per-wave fragment sources (chunk = 512 u16 = 1KB = 64 lanes x 16B)
  // A: chunks p*2+{0,1}; B (this wave's 32-col slice): chunks p*16 + wv*2 + {0,1}
  const u16* xsrc = xp + (size_t)slab * (32 * 2 * 512) + lane * 8;
  const u16* bsrc = wp + (size_t)t * (32 * 16 * 512) + (size_t)(wv * 2) * 512 + lane * 8;

  floatx16 ai[2], av[2];
#pragma unroll
  for (int m = 0; m < 2; ++m) { ai[m] = (floatx16)0.f; av[m] = (floatx16)0.f; }

  // 2-slot register ring; slot p&1 holds batch p. Refill happens AFTER the MFMAs
  // consume the slot (WAR resolved at issue), giving ~1 full phase of prefetch.
  short8 A0[2], A1[2], BI[2], BV[2];
#pragma unroll
  for (int pb = 0; pb < 2; ++pb) {
    A0[pb] = *(const short8*)(xsrc + pb * 1024);
    A1[pb] = *(const short8*)(xsrc + pb * 1024 + 512);
    BI[pb] = *(const short8*)(bsrc + (size_t)pb * 8192);
    BV[pb] = *(const short8*)(bsrc + (size_t)pb * 8192 + 512);
  }

#pragma unroll
  for (int p = 0; p < 32; ++p) {
    const int cur = p & 1;
    ai[0] = mfma32(A0[cur], BI[cur], ai[0]);
    ai[1] = mfma32(A1[cur], BI[cur], ai[1]);
    av[0] = mfma32(A0[cur], BV[cur], av[0]);
    av[1] = mfma32(A1[cur], BV[cur], av[1]);
    if (p < 30) {
      A0[cur] = *(const short8*)(xsrc + (p + 2) * 1024);
      A1[cur] = *(const short8*)(xsrc + (p + 2) * 1024 + 512);
      BI[cur] = *(const short8*)(bsrc + (size_t)(p + 2) * 8192);
      BV[cur] = *(const short8*)(bsrc + (size_t)(p + 2) * 8192 + 512);
    }
  }

  // ---- epilogue R13: dual-buffer, 3 syncs/mt ----
  const float inv_h = 1.0f / kH;
  float al[kIT];
#pragma unroll
  for (int i = 0; i < kIT; ++i) al[i] = alphas[t * kIT + i] * inv_h;

  const int row_r = tid >> 4;        // 0..31
  const int seg   = tid & 15;        // 0..15
  const int r4    = (row_r & 7) << 2;

#pragma unroll
  for (int mt = 0; mt < 2; ++mt) {
    __syncthreads();                 // prior users of sI/sV done
    // dump BOTH accumulators in one phase
#pragma unroll
    for (int q = 0; q < 16; ++q) {
      const int r  = (q & 3) + 8 * (q >> 2) + 4 * h;
      const int cs = (wv * 32 + l31) ^ ((r & 7) << 2);
      sI[r * 256 + cs] = ai[mt][q];
      sV[r * 256 + cs] = av[mt][q];
    }
    __syncthreads();

    // single read phase: xt (relu'd inhib) + a4 (value)
    float4 xt[4], a4[4];
#pragma unroll
    for (int j = 0; j < 4; ++j) {
      const int cb = (seg * 16 + 4 * j) ^ r4;
      xt[j] = *(const float4*)(sI + row_r * 256 + cb);
      a4[j] = *(const float4*)(sV + row_r * 256 + cb);
#pragma unroll
      for (int i = 0; i < 4; ++i) xt[j][i] = fmaxf(xt[j][i], 0.f);
    }

    // issue param loads early: overlap with the register-resident IT loop
    float4 sc[4], g4[4], b4[4];
#pragma unroll
    for (int j = 0; j < 4; ++j) {
      const int lc = seg * 16 + 4 * j;
      sc[j] = *(const float4*)(scales + t * kH + lc);
      g4[j] = *(const float4*)(gamma  + t * kH + lc);
      b4[j] = *(const float4*)(beta   + t * kH + lc);
    }

#pragma unroll
    for (int it = 0; it < kIT; ++it) {
      float4 s4 = xt[0];
#pragma unroll
      for (int j = 1; j < 4; ++j) s4 += xt[j];
      float v = s4.x + s4.y + s4.z + s4.w;
      v += __shfl_xor(v, 1, 16);
      v += __shfl_xor(v, 2, 16);
      v += __shfl_xor(v, 4, 16);
      v += __shfl_xor(v, 8, 16);
      const float m = al[it] * v;
#pragma unroll
      for (int j = 0; j < 4; ++j)
#pragma unroll
        for (int i = 0; i < 4; ++i) xt[j][i] = fmaxf(xt[j][i] - m, 0.f);
    }

    float4 res[4];
    float sum = 0.f, ssq = 0.f;
#pragma unroll
    for (int j = 0; j < 4; ++j) {
      float4 s;
#pragma unroll
      for (int i = 0; i < 4; ++i) {
        s[i] = sc[j][i] * xt[j][i] * a4[j][i];
        sum += s[i];
        ssq += s[i] * s[i];
      }
      res[j] = s;
    }
    sum += __shfl_xor(sum, 1, 16);  ssq += __shfl_xor(ssq, 1, 16);
    sum += __shfl_xor(sum, 2, 16);  ssq += __shfl_xor(ssq, 2, 16);
    sum += __shfl_xor(sum, 4, 16);  ssq += __shfl_xor(ssq, 4, 16);
    sum += __shfl_xor(sum, 8, 16);  ssq += __shfl_xor(ssq, 8, 16);
    const float mu  = sum * inv_h;
    const float var = ssq * inv_h - mu * mu;
    const float rs  = rsqrtf(var + kEPS);

#pragma unroll
    for (int j = 0; j < 4; ++j) {
      const int cb = (seg * 16 + 4 * j) ^ r4;
      float4 o;
#pragma unroll
      for (int i = 0; i < 4; ++i) o[i] = (res[j][i] - mu) * rs * g4[j][i] + b4[j][i];
      *(float4*)(sI + row_r * 256 + cb) = o;
    }
    __syncthreads();

    // coalesced non-temporal sweep: 8 waves x 4 rows
#pragma unroll
    for (int r8 = 0; r8 < 4; ++r8) {
      const int rr = wv * 4 + r8;
      const int rb = (rr & 7) << 2;
      const float4 v = *(const float4*)(sI + rr * 256 + ((4 * lane) ^ rb));
      ntstore4(out + (size_t)(slab * 64 + mt * 32 + rr) * (kT * kH) + t * kH + 4 * lane, v);
    }
  }
}

extern "C" void kernel_launch(void* const* d_in, const int* in_sizes, int n_in,
                              void* d_out, int out_size, void* d_ws, size_t ws_size,
                              hipStream_t stream) {
  const float* x      = (const float*)d_in[0];
  const float* w_in   = (const float*)d_in[1];
  const float* w_val  = (const float*)d_in[2];
  const float* alphas = (const float*)d_in[3];
  const float* scales = (const float*)d_in[4];
  const float* gamma  = (const float*)d_in[5];
  const float* beta   = (const float*)d_in[6];
  float* out = (float*)d_out;

  // ws: xp 4MB (64*32*2 chunks * 1KB) | wp 16MB (32*32*16 chunks * 1KB)
  u16* xp = (u16*)d_ws;
  u16* wp = xp + (size_t)64 * 32 * 2 * 512;

  pack_x_kernel<<<256, 256, 0, stream>>>(x, xp);
  pack_w_kernel<<<2048, 256, 0, stream>>>(w_in, w_val, wp);
  fused_kernel<<<kT * (kB / 64), 512, 0, stream>>>(xp, wp, alphas, scales,
                                                   gamma, beta, out);
}

// Round 10
// 311.354 us; speedup vs baseline: 1.1016x; 1.0064x over previous
//
#include <hip/hip_runtime.h>
#include <cstdint>

using u16 = unsigned short;
using u32 = unsigned int;

constexpr int kB  = 4096;
constexpr int kE  = 512;
constexpr int kT  = 32;
constexpr int kH  = 256;
constexpr int kIT = 5;
constexpr float kEPS = 1e-6f;

typedef __attribute__((ext_vector_type(8)))  short short8;
typedef __attribute__((ext_vector_type(16))) float floatx16;
typedef __attribute__((ext_vector_type(8)))  u16   ushort8;
typedef __attribute__((ext_vector_type(4)))  float floatv4;  // native vec for nt builtins

__device__ __forceinline__ u16 f2bf(float f) {
  u32 u = __builtin_bit_cast(u32, f);
  return (u16)((u + 0x7fffu + ((u >> 16) & 1u)) >> 16);
}

__device__ __forceinline__ floatx16 mfma32(short8 a, short8 b, floatx16 c) {
  return __builtin_amdgcn_mfma_f32_32x32x16_bf16(a, b, c, 0, 0, 0);
}

__device__ __forceinline__ void ntstore4(float* p, float4 v) {
  __builtin_nontemporal_store(__builtin_bit_cast(floatv4, v), (floatv4*)p);
}

// ---------------- pack_x (R6, verified): coalesced LDS transpose ----------------
// xp chunk c = slab*64 + ks*2 + mt ; lane l holds row=slab*64+mt*32+(l&31),
// k = ks*16+(l>>5)*8+j
__global__ __launch_bounds__(256) void pack_x_kernel(
    const float* __restrict__ x, u16* __restrict__ xp) {
  __shared__ __attribute__((aligned(16))) float tile[64 * 132];
  const int slab = blockIdx.x >> 2;
  const int kg   = blockIdx.x & 3;
  const int tid  = threadIdx.x;

  const int r0 = tid >> 5;          // 0..7
  const int c0 = (tid & 31) * 4;    // 0..124
#pragma unroll
  for (int p = 0; p < 8; ++p) {
    const int r = p * 8 + r0;
    const float4 v = *(const float4*)(x + (size_t)(slab * 64 + r) * kE + kg * 128 + c0);
    *(float4*)(tile + r * 132 + c0) = v;
  }
  __syncthreads();

  const int wv = tid >> 6, lane = tid & 63;
#pragma unroll
  for (int q = 0; q < 4; ++q) {
    const int cc   = wv * 4 + q;       // 0..15
    const int ks_l = cc >> 1;          // 0..7
    const int mt   = cc & 1;
    const int rl   = mt * 32 + (lane & 31);
    const int kl   = ks_l * 16 + (lane >> 5) * 8;
    const float4 f0 = *(const float4*)(tile + rl * 132 + kl);
    const float4 f1 = *(const float4*)(tile + rl * 132 + kl + 4);
    ushort8 o;
    o[0] = f2bf(f0.x); o[1] = f2bf(f0.y); o[2] = f2bf(f0.z); o[3] = f2bf(f0.w);
    o[4] = f2bf(f1.x); o[5] = f2bf(f1.y); o[6] = f2bf(f1.z); o[7] = f2bf(f1.w);
    const int c = slab * 64 + (kg * 8 + ks_l) * 2 + mt;
    *(ushort8*)(xp + (size_t)c * 512 + lane * 8) = o;
  }
}

// ---------------- pack_w (R6, verified): LDS transpose, cached loads ----------
// wp chunk c = t*512 + ks*16 + ntile*2 + mat : lane l holds n=ntile*32+(l&31),
// k=ks*16+(l>>5)*8+j
__global__ __launch_bounds__(256) void pack_w_kernel(
    const float* __restrict__ w_in, const float* __restrict__ w_val,
    u16* __restrict__ wp) {
  __shared__ __attribute__((aligned(16))) float tile[64 * 68];
  const int wb   = blockIdx.x;
  const int tl   = wb & 31;
  const int et   = tl >> 2;
  const int ht   = tl & 3;
  const int tm   = wb >> 5;
  const int t    = tm >> 1, mat = tm & 1;
  const int tid  = threadIdx.x;
  const float* src = (mat ? w_val : w_in) + (size_t)t * kE * kH +
                     (size_t)(et * 64) * kH + ht * 64;
  const int lrow = tid >> 4, lc4 = (tid & 15) * 4;
#pragma unroll
  for (int p = 0; p < 4; ++p) {
    const int e = lrow + p * 16;
    const float4 v = *(const float4*)(src + (size_t)e * kH + lc4);
    tile[e * 68 + lc4 + 0] = v.x; tile[e * 68 + lc4 + 1] = v.y;
    tile[e * 68 + lc4 + 2] = v.z; tile[e * 68 + lc4 + 3] = v.w;
  }
  __syncthreads();
  const int ks_l = tid >> 6, lane = tid & 63;
  const int kloc = ks_l * 16 + (lane >> 5) * 8;
#pragma unroll
  for (int nt_l = 0; nt_l < 2; ++nt_l) {
    const int nloc = nt_l * 32 + (lane & 31);
    ushort8 o;
#pragma unroll
    for (int j = 0; j < 8; ++j) o[j] = f2bf(tile[(kloc + j) * 68 + nloc]);
    const int c = t * 512 + (et * 4 + ks_l) * 16 + (ht * 2 + nt_l) * 2 + mat;
    *(ushort8*)(wp + (size_t)c * 512 + lane * 8) = o;
  }
}

// ---------------- fused R14: R10 K-loop (frozen) + 3-sync epilogue, NO spill ----
// R13's regression was scratch spill (FETCH+39/WRITE+78MB): hoisting a4/sc/g4/b4
// put 112 floats live across the IT loop against a 128-reg unified cap. R14 keeps
// the dual-buffer 3-sync structure but restores R10's register discipline: only
// xt[4] lives across IT; a4 read from sV per-j INSIDE the res loop; sc/g4/b4
// per-j at use. Controlled A/B: 3-sync structure vs R10's 6-sync, no reg confound.
__global__ __launch_bounds__(512, 4) void fused_kernel(
    const u16* __restrict__ xp, const u16* __restrict__ wp,
    const float* __restrict__ alphas, const float* __restrict__ scales,
    const float* __restrict__ gamma, const float* __restrict__ beta,
    float* __restrict__ out) {
  __shared__ __attribute__((aligned(16))) float sI[32 * 256];  // 32KB
  __shared__ __attribute__((aligned(16))) float sV[32 * 256];  // 32KB

  const int tid  = threadIdx.x;
  const int wv   = tid >> 6;         // 0..7
  const int lane = tid & 63;
  const int l31  = lane & 31;
  const int h    = lane >> 5;

  const int bid  = blockIdx.x;
  const int xcd  = bid & 7;
  const int r_   = bid >> 3;
  const int st   = r_ >> 6;
  const int wi   = r_ & 63;
  const int t    = xcd * 4 + (wi >> 4);
  const int slab = st * 16 + (wi & 15);

  // per-wave fragment sources (chunk = 512 u16 = 1KB = 64 lanes x 16B)
  // A: chunks p*2+{0,1}; B (this wave's 32-col slice): chunks p*16 + wv*2 + {0,1}
  const u16* xsrc = xp + (size_t)slab * (32 * 2 * 512) + lane * 8;
  const u16* bsrc = wp + (size_t)t * (32 * 16 * 512) + (size_t)(wv * 2) * 512 + lane * 8;

  floatx16 ai[2], av[2];
#pragma unroll
  for (int m = 0; m < 2; ++m) { ai[m] = (floatx16)0.f; av[m] = (floatx16)0.f; }

  // 2-slot register ring; slot p&1 holds batch p. Refill happens AFTER the MFMAs
  // consume the slot (WAR resolved at issue), giving ~1 full phase of prefetch.
  short8 A0[2], A1[2], BI[2], BV[2];
#pragma unroll
  for (int pb = 0; pb < 2; ++pb) {
    A0[pb] = *(const short8*)(xsrc + pb * 1024);
    A1[pb] = *(const short8*)(xsrc + pb * 1024 + 512);
    BI[pb] = *(const short8*)(bsrc + (size_t)pb * 8192);
    BV[pb] = *(const short8*)(bsrc + (size_t)pb * 8192 + 512);
  }

#pragma unroll
  for (int p = 0; p < 32; ++p) {
    const int cur = p & 1;
    ai[0] = mfma32(A0[cur], BI[cur], ai[0]);
    ai[1] = mfma32(A1[cur], BI[cur], ai[1]);
    av[0] = mfma32(A0[cur], BV[cur], av[0]);
    av[1] = mfma32(A1[cur], BV[cur], av[1]);
    if (p < 30) {
      A0[cur] = *(const short8*)(xsrc + (p + 2) * 1024);
      A1[cur] = *(const short8*)(xsrc + (p + 2) * 1024 + 512);
      BI[cur] = *(const short8*)(bsrc + (size_t)(p + 2) * 8192);
      BV[cur] = *(const short8*)(bsrc + (size_t)(p + 2) * 8192 + 512);
    }
  }

  // ---- epilogue R14: dual-buffer, 3 syncs/mt, R10 register discipline ----
  const float inv_h = 1.0f / kH;
  float al[kIT];
#pragma unroll
  for (int i = 0; i < kIT; ++i) al[i] = alphas[t * kIT + i] * inv_h;

  const int row_r = tid >> 4;        // 0..31
  const int seg   = tid & 15;        // 0..15
  const int r4    = (row_r & 7) << 2;

#pragma unroll
  for (int mt = 0; mt < 2; ++mt) {
    __syncthreads();                 // prior users of sI/sV done
    // dump BOTH accumulators in one phase
#pragma unroll
    for (int q = 0; q < 16; ++q) {
      const int r  = (q & 3) + 8 * (q >> 2) + 4 * h;
      const int cs = (wv * 32 + l31) ^ ((r & 7) << 2);
      sI[r * 256 + cs] = ai[mt][q];
      sV[r * 256 + cs] = av[mt][q];
    }
    __syncthreads();

    // read phase: xt only (16 regs live across IT loop)
    float4 xt[4];
#pragma unroll
    for (int j = 0; j < 4; ++j) {
      xt[j] = *(const float4*)(sI + row_r * 256 + ((seg * 16 + 4 * j) ^ r4));
#pragma unroll
      for (int i = 0; i < 4; ++i) xt[j][i] = fmaxf(xt[j][i], 0.f);
    }

#pragma unroll
    for (int it = 0; it < kIT; ++it) {
      float4 s4 = xt[0];
#pragma unroll
      for (int j = 1; j < 4; ++j) s4 += xt[j];
      float v = s4.x + s4.y + s4.z + s4.w;
      v += __shfl_xor(v, 1, 16);
      v += __shfl_xor(v, 2, 16);
      v += __shfl_xor(v, 4, 16);
      v += __shfl_xor(v, 8, 16);
      const float m = al[it] * v;
#pragma unroll
      for (int j = 0; j < 4; ++j)
#pragma unroll
        for (int i = 0; i < 4; ++i) xt[j][i] = fmaxf(xt[j][i] - m, 0.f);
    }

    // res loop: a4 from sV + sc per-j (short live ranges, as in R10)
    float4 res[4];
    float sum = 0.f, ssq = 0.f;
#pragma unroll
    for (int j = 0; j < 4; ++j) {
      const int lc = seg * 16 + 4 * j;           // logical column
      const int cb = lc ^ r4;                    // physical LDS offset
      const float4 a4 = *(const float4*)(sV + row_r * 256 + cb);
      const float4 sc = *(const float4*)(scales + t * kH + lc);
      float4 s;
#pragma unroll
      for (int i = 0; i < 4; ++i) {
        s[i] = sc[i] * xt[j][i] * a4[i];
        sum += s[i];
        ssq += s[i] * s[i];
      }
      res[j] = s;
    }
    sum += __shfl_xor(sum, 1, 16);  ssq += __shfl_xor(ssq, 1, 16);
    sum += __shfl_xor(sum, 2, 16);  ssq += __shfl_xor(ssq, 2, 16);
    sum += __shfl_xor(sum, 4, 16);  ssq += __shfl_xor(ssq, 4, 16);
    sum += __shfl_xor(sum, 8, 16);  ssq += __shfl_xor(ssq, 8, 16);
    const float mu  = sum * inv_h;
    const float var = ssq * inv_h - mu * mu;
    const float rs  = rsqrtf(var + kEPS);

#pragma unroll
    for (int j = 0; j < 4; ++j) {
      const int lc = seg * 16 + 4 * j;
      const int cb = lc ^ r4;
      const float4 g4 = *(const float4*)(gamma + t * kH + lc);
      const float4 b4 = *(const float4*)(beta + t * kH + lc);
      float4 o;
#pragma unroll
      for (int i = 0; i < 4; ++i) o[i] = (res[j][i] - mu) * rs * g4[i] + b4[i];
      *(float4*)(sI + row_r * 256 + cb) = o;
    }
    __syncthreads();

    // coalesced non-temporal sweep: 8 waves x 4 rows
#pragma unroll
    for (int r8 = 0; r8 < 4; ++r8) {
      const int rr = wv * 4 + r8;
      const int rb = (rr & 7) << 2;
      const float4 v = *(const float4*)(sI + rr * 256 + ((4 * lane) ^ rb));
      ntstore4(out + (size_t)(slab * 64 + mt * 32 + rr) * (kT * kH) + t * kH + 4 * lane, v);
    }
  }
}

extern "C" void kernel_launch(void* const* d_in, const int* in_sizes, int n_in,
                              void* d_out, int out_size, void* d_ws, size_t ws_size,
                              hipStream_t stream) {
  const float* x      = (const float*)d_in[0];
  const float* w_in   = (const float*)d_in[1];
  const float* w_val  = (const float*)d_in[2];
  const float* alphas = (const float*)d_in[3];
  const float* scales = (const float*)d_in[4];
  const float* gamma  = (const float*)d_in[5];
  const float* beta   = (const float*)d_in[6];
  float* out = (float*)d_out;

  // ws: xp 4MB (64*32*2 chunks * 1KB) | wp 16MB (32*32*16 chunks * 1KB)
  u16* xp = (u16*)d_ws;
  u16* wp = xp + (size_t)64 * 32 * 2 * 512;

  pack_x_kernel<<<256, 256, 0, stream>>>(x, xp);
  pack_w_kernel<<<2048, 256, 0, stream>>>(w_in, w_val, wp);
  fused_kernel<<<kT * (kB / 64), 512, 0, stream>>>(xp, wp, alphas, scales,
                                                   gamma, beta, out);
}

// Round 11
// 291.589 us; speedup vs baseline: 1.1763x; 1.0678x over previous
//
#include <hip/hip_runtime.h>
#include <cstdint>

using u16 = unsigned short;
using u32 = unsigned int;

constexpr int kB  = 4096;
constexpr int kE  = 512;
constexpr int kT  = 32;
constexpr int kH  = 256;
constexpr int kIT = 5;
constexpr float kEPS = 1e-6f;

typedef __attribute__((ext_vector_type(8)))  short short8;
typedef __attribute__((ext_vector_type(16))) float floatx16;
typedef __attribute__((ext_vector_type(8)))  u16   ushort8;
typedef __attribute__((ext_vector_type(4)))  float floatv4;  // native vec for nt builtins

__device__ __forceinline__ u16 f2bf(float f) {
  u32 u = __builtin_bit_cast(u32, f);
  return (u16)((u + 0x7fffu + ((u >> 16) & 1u)) >> 16);
}

__device__ __forceinline__ floatx16 mfma32(short8 a, short8 b, floatx16 c) {
  return __builtin_amdgcn_mfma_f32_32x32x16_bf16(a, b, c, 0, 0, 0);
}

__device__ __forceinline__ void ntstore4(float* p, float4 v) {
  __builtin_nontemporal_store(__builtin_bit_cast(floatv4, v), (floatv4*)p);
}

// ---------------- pack_x (R6, verified): coalesced LDS transpose ----------------
// xp chunk c = slab*64 + ks*2 + mt ; lane l holds row=slab*64+mt*32+(l&31),
// k = ks*16+(l>>5)*8+j
__global__ __launch_bounds__(256) void pack_x_kernel(
    const float* __restrict__ x, u16* __restrict__ xp) {
  __shared__ __attribute__((aligned(16))) float tile[64 * 132];
  const int slab = blockIdx.x >> 2;
  const int kg   = blockIdx.x & 3;
  const int tid  = threadIdx.x;

  const int r0 = tid >> 5;          // 0..7
  const int c0 = (tid & 31) * 4;    // 0..124
#pragma unroll
  for (int p = 0; p < 8; ++p) {
    const int r = p * 8 + r0;
    const float4 v = *(const float4*)(x + (size_t)(slab * 64 + r) * kE + kg * 128 + c0);
    *(float4*)(tile + r * 132 + c0) = v;
  }
  __syncthreads();

  const int wv = tid >> 6, lane = tid & 63;
#pragma unroll
  for (int q = 0; q < 4; ++q) {
    const int cc   = wv * 4 + q;       // 0..15
    const int ks_l = cc >> 1;          // 0..7
    const int mt   = cc & 1;
    const int rl   = mt * 32 + (lane & 31);
    const int kl   = ks_l * 16 + (lane >> 5) * 8;
    const float4 f0 = *(const float4*)(tile + rl * 132 + kl);
    const float4 f1 = *(const float4*)(tile + rl * 132 + kl + 4);
    ushort8 o;
    o[0] = f2bf(f0.x); o[1] = f2bf(f0.y); o[2] = f2bf(f0.z); o[3] = f2bf(f0.w);
    o[4] = f2bf(f1.x); o[5] = f2bf(f1.y); o[6] = f2bf(f1.z); o[7] = f2bf(f1.w);
    const int c = slab * 64 + (kg * 8 + ks_l) * 2 + mt;
    *(ushort8*)(xp + (size_t)c * 512 + lane * 8) = o;
  }
}

// ---------------- pack_w (R6, verified): LDS transpose, cached loads ----------
// wp chunk c = t*512 + ks*16 + ntile*2 + mat : lane l holds n=ntile*32+(l&31),
// k=ks*16+(l>>5)*8+j
__global__ __launch_bounds__(256) void pack_w_kernel(
    const float* __restrict__ w_in, const float* __restrict__ w_val,
    u16* __restrict__ wp) {
  __shared__ __attribute__((aligned(16))) float tile[64 * 68];
  const int wb   = blockIdx.x;
  const int tl   = wb & 31;
  const int et   = tl >> 2;
  const int ht   = tl & 3;
  const int tm   = wb >> 5;
  const int t    = tm >> 1, mat = tm & 1;
  const int tid  = threadIdx.x;
  const float* src = (mat ? w_val : w_in) + (size_t)t * kE * kH +
                     (size_t)(et * 64) * kH + ht * 64;
  const int lrow = tid >> 4, lc4 = (tid & 15) * 4;
#pragma unroll
  for (int p = 0; p < 4; ++p) {
    const int e = lrow + p * 16;
    const float4 v = *(const float4*)(src + (size_t)e * kH + lc4);
    tile[e * 68 + lc4 + 0] = v.x; tile[e * 68 + lc4 + 1] = v.y;
    tile[e * 68 + lc4 + 2] = v.z; tile[e * 68 + lc4 + 3] = v.w;
  }
  __syncthreads();
  const int ks_l = tid >> 6, lane = tid & 63;
  const int kloc = ks_l * 16 + (lane >> 5) * 8;
#pragma unroll
  for (int nt_l = 0; nt_l < 2; ++nt_l) {
    const int nloc = nt_l * 32 + (lane & 31);
    ushort8 o;
#pragma unroll
    for (int j = 0; j < 8; ++j) o[j] = f2bf(tile[(kloc + j) * 68 + nloc]);
    const int c = t * 512 + (et * 4 + ks_l) * 16 + (ht * 2 + nt_l) * 2 + mat;
    *(ushort8*)(wp + (size_t)c * 512 + lane * 8) = o;
  }
}

// ---------------- fused R15: R10 K-loop (frozen) + spill-free 16-row epilogue ---
// Diagnosis R13/R14: ALL prior epilogues spill (even R10: WRITE 205 vs 131 output)
// because the 64-reg accumulator file stays live for mt=1 while the 32-row
// epilogue needs ~55 arch regs against the 64-arch cap of (512,4). Fix: 16-row
// half-tile rounds (4 = mt x half): 32 thr/row, 8 H/thread -> xt[2]+res[2]=16
// live regs; peak ~109 of 128 unified -> NO spill. Acc split: q in [half*8,+8)
// maps to local row rl=(q8&3)+8*(q8>>2)+4h in [0,16), same XOR-swizzle family
// (rl = r mod 16, rl&7 preserved). sI/sV 16KB each. 12 barriers vs 6: cheap
// against ~125MB of removed scratch HBM traffic.
__global__ __launch_bounds__(512, 4) void fused_kernel(
    const u16* __restrict__ xp, const u16* __restrict__ wp,
    const float* __restrict__ alphas, const float* __restrict__ scales,
    const float* __restrict__ gamma, const float* __restrict__ beta,
    float* __restrict__ out) {
  __shared__ __attribute__((aligned(16))) float sI[16 * 256];  // 16KB
  __shared__ __attribute__((aligned(16))) float sV[16 * 256];  // 16KB

  const int tid  = threadIdx.x;
  const int wv   = tid >> 6;         // 0..7
  const int lane = tid & 63;
  const int l31  = lane & 31;
  const int h    = lane >> 5;

  const int bid  = blockIdx.x;
  const int xcd  = bid & 7;
  const int r_   = bid >> 3;
  const int st   = r_ >> 6;
  const int wi   = r_ & 63;
  const int t    = xcd * 4 + (wi >> 4);
  const int slab = st * 16 + (wi & 15);

  // per-wave fragment sources (chunk = 512 u16 = 1KB = 64 lanes x 16B)
  // A: chunks p*2+{0,1}; B (this wave's 32-col slice): chunks p*16 + wv*2 + {0,1}
  const u16* xsrc = xp + (size_t)slab * (32 * 2 * 512) + lane * 8;
  const u16* bsrc = wp + (size_t)t * (32 * 16 * 512) + (size_t)(wv * 2) * 512 + lane * 8;

  floatx16 ai[2], av[2];
#pragma unroll
  for (int m = 0; m < 2; ++m) { ai[m] = (floatx16)0.f; av[m] = (floatx16)0.f; }

  // 2-slot register ring; slot p&1 holds batch p (R10, frozen).
  short8 A0[2], A1[2], BI[2], BV[2];
#pragma unroll
  for (int pb = 0; pb < 2; ++pb) {
    A0[pb] = *(const short8*)(xsrc + pb * 1024);
    A1[pb] = *(const short8*)(xsrc + pb * 1024 + 512);
    BI[pb] = *(const short8*)(bsrc + (size_t)pb * 8192);
    BV[pb] = *(const short8*)(bsrc + (size_t)pb * 8192 + 512);
  }

#pragma unroll
  for (int p = 0; p < 32; ++p) {
    const int cur = p & 1;
    ai[0] = mfma32(A0[cur], BI[cur], ai[0]);
    ai[1] = mfma32(A1[cur], BI[cur], ai[1]);
    av[0] = mfma32(A0[cur], BV[cur], av[0]);
    av[1] = mfma32(A1[cur], BV[cur], av[1]);
    if (p < 30) {
      A0[cur] = *(const short8*)(xsrc + (p + 2) * 1024);
      A1[cur] = *(const short8*)(xsrc + (p + 2) * 1024 + 512);
      BI[cur] = *(const short8*)(bsrc + (size_t)(p + 2) * 8192);
      BV[cur] = *(const short8*)(bsrc + (size_t)(p + 2) * 8192 + 512);
    }
  }

  // ---- epilogue R15: 4 x 16-row rounds, spill-free ----
  const float inv_h = 1.0f / kH;
  float al[kIT];
#pragma unroll
  for (int i = 0; i < kIT; ++i) al[i] = alphas[t * kIT + i] * inv_h;

  const int row_r = tid >> 5;        // 0..15
  const int seg   = tid & 31;        // 0..31 (8 H each)
  const int r4    = (row_r & 7) << 2;

#pragma unroll
  for (int rd = 0; rd < 4; ++rd) {
    const int mt   = rd >> 1;
    const int half = rd & 1;
    __syncthreads();                 // prior round's users of sI/sV done
    // dump this half's 8 acc values (I and V) in one phase
#pragma unroll
    for (int q8 = 0; q8 < 8; ++q8) {
      const int q  = half * 8 + q8;
      const int rl = (q8 & 3) + 8 * (q8 >> 2) + 4 * h;   // 0..15
      const int cs = (wv * 32 + l31) ^ ((rl & 7) << 2);
      sI[rl * 256 + cs] = ai[mt][q];
      sV[rl * 256 + cs] = av[mt][q];
    }
    __syncthreads();

    // read phase: xt only (8 regs live across IT loop)
    float4 xt[2];
#pragma unroll
    for (int j = 0; j < 2; ++j) {
      xt[j] = *(const float4*)(sI + row_r * 256 + ((seg * 8 + 4 * j) ^ r4));
#pragma unroll
      for (int i = 0; i < 4; ++i) xt[j][i] = fmaxf(xt[j][i], 0.f);
    }

#pragma unroll
    for (int it = 0; it < kIT; ++it) {
      float4 s4 = xt[0] + xt[1];
      float v = s4.x + s4.y + s4.z + s4.w;
      v += __shfl_xor(v, 1, 32);
      v += __shfl_xor(v, 2, 32);
      v += __shfl_xor(v, 4, 32);
      v += __shfl_xor(v, 8, 32);
      v += __shfl_xor(v, 16, 32);
      const float m = al[it] * v;
#pragma unroll
      for (int j = 0; j < 2; ++j)
#pragma unroll
        for (int i = 0; i < 4; ++i) xt[j][i] = fmaxf(xt[j][i] - m, 0.f);
    }

    // res loop: a4 from sV + sc per-j (short live ranges)
    float4 res[2];
    float sum = 0.f, ssq = 0.f;
#pragma unroll
    for (int j = 0; j < 2; ++j) {
      const int lc = seg * 8 + 4 * j;            // logical column
      const int cb = lc ^ r4;                    // physical LDS offset
      const float4 a4 = *(const float4*)(sV + row_r * 256 + cb);
      const float4 sc = *(const float4*)(scales + t * kH + lc);
      float4 s;
#pragma unroll
      for (int i = 0; i < 4; ++i) {
        s[i] = sc[i] * xt[j][i] * a4[i];
        sum += s[i];
        ssq += s[i] * s[i];
      }
      res[j] = s;
    }
    sum += __shfl_xor(sum, 1, 32);   ssq += __shfl_xor(ssq, 1, 32);
    sum += __shfl_xor(sum, 2, 32);   ssq += __shfl_xor(ssq, 2, 32);
    sum += __shfl_xor(sum, 4, 32);   ssq += __shfl_xor(ssq, 4, 32);
    sum += __shfl_xor(sum, 8, 32);   ssq += __shfl_xor(ssq, 8, 32);
    sum += __shfl_xor(sum, 16, 32);  ssq += __shfl_xor(ssq, 16, 32);
    const float mu  = sum * inv_h;
    const float var = ssq * inv_h - mu * mu;
    const float rs  = rsqrtf(var + kEPS);

#pragma unroll
    for (int j = 0; j < 2; ++j) {
      const int lc = seg * 8 + 4 * j;
      const int cb = lc ^ r4;
      const float4 g4 = *(const float4*)(gamma + t * kH + lc);
      const float4 b4 = *(const float4*)(beta + t * kH + lc);
      float4 o;
#pragma unroll
      for (int i = 0; i < 4; ++i) o[i] = (res[j][i] - mu) * rs * g4[i] + b4[i];
      *(float4*)(sI + row_r * 256 + cb) = o;
    }
    __syncthreads();

    // coalesced non-temporal sweep: 16 rows x 64 float4; 8 waves x 2 rows
#pragma unroll
    for (int k = 0; k < 2; ++k) {
      const int rr = wv * 2 + k;
      const int rb = (rr & 7) << 2;
      const float4 v = *(const float4*)(sI + rr * 256 + ((4 * lane) ^ rb));
      ntstore4(out + (size_t)(slab * 64 + mt * 32 + half * 16 + rr) * (kT * kH)
                   + t * kH + 4 * lane, v);
    }
  }
}

extern "C" void kernel_launch(void* const* d_in, const int* in_sizes, int n_in,
                              void* d_out, int out_size, void* d_ws, size_t ws_size,
                              hipStream_t stream) {
  const float* x      = (const float*)d_in[0];
  const float* w_in   = (const float*)d_in[1];
  const float* w_val  = (const float*)d_in[2];
  const float* alphas = (const float*)d_in[3];
  const float* scales = (const float*)d_in[4];
  const float* gamma  = (const float*)d_in[5];
  const float* beta   = (const float*)d_in[6];
  float* out = (float*)d_out;

  // ws: xp 4MB (64*32*2 chunks * 1KB) | wp 16MB (32*32*16 chunks * 1KB)
  u16* xp = (u16*)d_ws;
  u16* wp = xp + (size_t)64 * 32 * 2 * 512;

  pack_x_kernel<<<256, 256, 0, stream>>>(x, xp);
  pack_w_kernel<<<2048, 256, 0, stream>>>(w_in, w_val, wp);
  fused_kernel<<<kT * (kB / 64), 512, 0, stream>>>(xp, wp, alphas, scales,
                                                   gamma, beta, out);
}